// Round 15
// baseline (337.682 us; speedup 1.0000x reference)
//
#include <hip/hip_runtime.h>
#include <hip/hip_bf16.h>

#define FEAT 128

typedef unsigned int uint32;
typedef unsigned short ushort16;
typedef __attribute__((ext_vector_type(8))) short short8;
typedef __attribute__((ext_vector_type(4))) float v4f;
typedef __attribute__((ext_vector_type(2))) float f32x2;

// ---- bf16 helpers (RNE round; bf16->f32 is exact shift) ---------------------
__device__ __forceinline__ ushort16 f2bf(float f) {
    uint32 u = __float_as_uint(f);
    u += 0x7fffu + ((u >> 16) & 1u);
    return (ushort16)(u >> 16);
}
__device__ __forceinline__ float bflo(uint32 u) { return __uint_as_float(u << 16); }
__device__ __forceinline__ float bfhi(uint32 u) { return __uint_as_float(u & 0xffff0000u); }
__device__ __forceinline__ f32x2 up2(uint32 u) { return (f32x2){bflo(u), bfhi(u)}; }

// ---------------- shared gemm body: half-W-per-wave register-resident --------
// (R6 design, frozen). OPERAND SWAP (verified R4): mfma(Wfrag, Afrag) ->
// lane holds 4 consecutive W-cols of node row l16 -> direct 8B stores.
__device__ __forceinline__ void gemm_body(const float* __restrict__ A,
                                          const ushort16* __restrict__ Wt,
                                          ushort16* __restrict__ Ch, int n,
                                          int pairId, int pairStride,
                                          int tile0, int tile1, int t) {
    const int w = t >> 6;
    const int lane = t & 63;
    const int quad = lane >> 4;
    const int l16 = lane & 15;
    const int colBase = (w & 1) * 64;

    short8 wf[4][4];
#pragma unroll
    for (int ct = 0; ct < 4; ct++) {
        const ushort16* wp = Wt + (size_t)(colBase + ct * 16 + l16) * FEAT + quad * 8;
#pragma unroll
        for (int ks = 0; ks < 4; ks++) wf[ct][ks] = *(const short8*)(wp + ks * 32);
    }

    int tile = tile0 + pairId;
    if (tile >= tile1) return;

    auto loadA = [&](int tl, short8 (&a)[4]) {
        const int rowi = tl * 16 + l16;
        if (rowi < n) {
#pragma unroll
            for (int ks = 0; ks < 4; ks++) {
                const float* ap = A + (size_t)rowi * FEAT + quad * 8 + ks * 32;
                float4 f0 = *(const float4*)ap;
                float4 f1 = *(const float4*)(ap + 4);
                short8 v;
                v[0] = f2bf(f0.x); v[1] = f2bf(f0.y); v[2] = f2bf(f0.z); v[3] = f2bf(f0.w);
                v[4] = f2bf(f1.x); v[5] = f2bf(f1.y); v[6] = f2bf(f1.z); v[7] = f2bf(f1.w);
                a[ks] = v;
            }
        } else {
#pragma unroll
            for (int ks = 0; ks < 4; ks++) a[ks] = (short8)0;
        }
    };

    short8 aCur[4];
    loadA(tile, aCur);

    while (tile < tile1) {
        const int nextTile = tile + pairStride;
        short8 aNxt[4];
        if (nextTile < tile1) loadA(nextTile, aNxt);

        v4f acc[4];
#pragma unroll
        for (int ct = 0; ct < 4; ct++) acc[ct] = (v4f)0.f;
#pragma unroll
        for (int ct = 0; ct < 4; ct++)
#pragma unroll
            for (int ks = 0; ks < 4; ks++)
                acc[ct] = __builtin_amdgcn_mfma_f32_16x16x32_bf16(wf[ct][ks], aCur[ks], acc[ct], 0, 0, 0);

        const int rowi = tile * 16 + l16;
        if (rowi < n) {
#pragma unroll
            for (int ct = 0; ct < 4; ct++) {
                uint2 o;
                o.x = (uint32)f2bf(acc[ct][0]) | ((uint32)f2bf(acc[ct][1]) << 16);
                o.y = (uint32)f2bf(acc[ct][2]) | ((uint32)f2bf(acc[ct][3]) << 16);
                *(uint2*)(Ch + (size_t)rowi * FEAT + colBase + ct * 16 + quad * 4) = o;
            }
        }

        tile = nextTile;
#pragma unroll
        for (int ks = 0; ks < 4; ks++) aCur[ks] = aNxt[ks];
    }
}

// ---------------- pre: zero counts + W01=W0@W1 + zero(P) ---------------------
__global__ __launch_bounds__(256) void pre_kernel(int* __restrict__ counts, int n,
                                                  const float* __restrict__ W0,
                                                  const float* __restrict__ W1,
                                                  ushort16* __restrict__ W01t,
                                                  float* __restrict__ Pbuf) {
    int b = blockIdx.x;
    int t = threadIdx.x;
    if (b < 100) {
        int idx = (b * 256 + t) * 4;
        if (idx + 3 < n) {
            *(int4*)(counts + idx) = make_int4(0, 0, 0, 0);
        } else {
            for (int i = idx; i < n; i++) counts[i] = 0;
        }
    } else if (b < 164) {
        __shared__ float sW0[2][FEAT];
        int wb = b - 100;  // [0, 64)
        int lk = t >> 7;
        int ncol = t & 127;
        int k = wb * 2 + lk;
        sW0[lk][ncol] = W0[(size_t)k * FEAT + ncol];
        __syncthreads();
        float acc = 0.f;
#pragma unroll 4
        for (int j = 0; j < FEAT; j++)
            acc += sW0[lk][j] * W1[(size_t)j * FEAT + ncol];
        W01t[(size_t)ncol * FEAT + k] = f2bf(acc);  // [n][k], transposed for MFMA
    } else {
        int zb = b - 164;  // [0, 32): 512*128 floats
        float4 z = make_float4(0.f, 0.f, 0.f, 0.f);
        float* p = Pbuf + (size_t)zb * 2048 + t * 8;
        *(float4*)p = z;
        *(float4*)(p + 4) = z;
    }
}

// ---------------- FUSED hist + gemm tiles [0,1750) ---------------------------
// R15 rebalance: hist (~22us) was over-covered by half the gemm; shrink its
// share so the dispatch ~= max(hist, gemm slice).
__global__ __launch_bounds__(256) void histgemmA_kernel(const int* __restrict__ col,
                                                        int* __restrict__ counts, int E,
                                                        const float* __restrict__ A,
                                                        const ushort16* __restrict__ Wt,
                                                        ushort16* __restrict__ Ch, int n) {
    const int b = blockIdx.x;
    const int r9 = b % 9;
    const int g9 = b / 9;
    const int t = threadIdx.x;
    if (r9 >= 4) {
        int hb = g9 * 5 + (r9 - 4);  // hist block id in [0, 640)
        int id = hb * 256 + t;
        if (id * 4 + 3 < E) {
            int4 c4 = *(const int4*)(col + id * 4);
            atomicAdd(&counts[c4.x], 1);
            atomicAdd(&counts[c4.y], 1);
            atomicAdd(&counts[c4.z], 1);
            atomicAdd(&counts[c4.w], 1);
        } else {
            for (int e = id * 4; e < E; e++) atomicAdd(&counts[col[e]], 1);
        }
        return;
    }
    int gb = g9 * 4 + r9;  // [0, 512) -> 1024 pairs
    gemm_body(A, Wt, Ch, n, gb * 2 + ((t >> 6) >> 1), 1024, 0, 1750, t);
}

// ---------------- scan step 1: per-1024-chunk sums ---------------------------
__global__ __launch_bounds__(256) void scan_part(const int* __restrict__ counts,
                                                 int* __restrict__ bsum, int n) {
    __shared__ int s[256];
    int base = blockIdx.x * 1024;
    int t = threadIdx.x;
    int v = 0;
#pragma unroll
    for (int i = 0; i < 4; i++) {
        int idx = base + t * 4 + i;
        if (idx < n) v += counts[idx];
    }
    s[t] = v;
    __syncthreads();
    for (int o = 128; o > 0; o >>= 1) {
        if (t < o) s[t] += s[t + o];
        __syncthreads();
    }
    if (t == 0) bsum[blockIdx.x] = s[0];
}

// ---------------- FUSED scan_final + gemm tiles [1750,2500) ------------------
// scan role: blocks [0,98) (launch first -> run concurrently with gemm blocks)
__global__ __launch_bounds__(256) void scanfinalgemm_kernel(
        const int* __restrict__ counts, const int* __restrict__ bsum,
        int* __restrict__ off, int* __restrict__ nxt,
        float* __restrict__ dinv, int n, int nb,
        const float* __restrict__ A, const ushort16* __restrict__ Wt,
        ushort16* __restrict__ Ch) {
    const int b = blockIdx.x;
    const int t = threadIdx.x;
    if (b >= nb) {
        int gb = b - nb;  // [0, 384) -> 768 pairs
        gemm_body(A, Wt, Ch, n, gb * 2 + ((t >> 6) >> 1), 768, 1750, 2500, t);
        return;
    }
    __shared__ int s[256];
    __shared__ int sb[128];
    int base = b * 1024;
    if (t < nb) sb[t] = bsum[t];
    int c[4];
    int sum = 0;
#pragma unroll
    for (int i = 0; i < 4; i++) {
        int idx = base + t * 4 + i;
        c[i] = (idx < n) ? counts[idx] : 0;
        sum += c[i];
    }
    int v0 = sum;
    s[t] = sum;
    __syncthreads();
    for (int o = 1; o < 256; o <<= 1) {
        int v = (t >= o) ? s[t - o] : 0;
        __syncthreads();
        s[t] += v;
        __syncthreads();
    }
    int blockBase = 0;
    for (int j = 0; j < b; j++) blockBase += sb[j];
    int excl = s[t] - v0 + blockBase;
#pragma unroll
    for (int i = 0; i < 4; i++) {
        int idx = base + t * 4 + i;
        if (idx < n) {
            off[idx] = excl;
            nxt[idx] = excl;
            dinv[idx] = rsqrtf((float)(c[i] + 1));  // +1 = self loop
        }
        excl += c[i];
    }
    if (b == nb - 1 && t == 255) off[n] = excl;  // == E
}

// ---------------- FUSED fill + gemm tiles [2500,6250) ------------------------
// fill (latency-bound ~47us alone) absorbs the largest gemm share for free.
__global__ __launch_bounds__(256) void fillgemmB_kernel(const float* __restrict__ A,
                                                        const ushort16* __restrict__ Wt,
                                                        ushort16* __restrict__ Ch, int n,
                                                        const int* __restrict__ row,
                                                        const int* __restrict__ col,
                                                        int* __restrict__ nxt,
                                                        int* __restrict__ srcArr, int E) {
    const int b = blockIdx.x;
    const int r7 = b % 7;
    const int g7 = b / 7;
    const int t = threadIdx.x;
    if (r7 >= 2) {
        int fb = g7 * 5 + (r7 - 2);  // fill block id in [0, 2560)
        int e = fb * 256 + t;
        if (e < E) {
            int c = col[e], r = row[e];
            int p = atomicAdd(&nxt[c], 1);
            __builtin_nontemporal_store(r, &srcArr[p]);
        }
        return;
    }
    int gb = g7 * 2 + r7;  // [0, 1024) -> 2048 pairs
    gemm_body(A, Wt, Ch, n, gb * 2 + ((t >> 6) >> 1), 2048, 2500, 6250, t);
}

// ---------------- gather body (shared): returns row b[8] for this lane -------
// H[c] = dinv[c]^2*T[c] + sum_e dinv[c]*dinv[src_e]*T[src_e].
// 4 edge-groups x 16 lanes x 16B, unroll-2. Measured floor ~48us.
__device__ __forceinline__ void gather_body(const int* __restrict__ off,
                                            const int* __restrict__ srcArr,
                                            const float* __restrict__ dinv,
                                            const uint4* __restrict__ table,
                                            int node, int lane, float* b) {
    int grp = lane >> 4;
    int l16 = lane & 15;
    float dc = dinv[node];

    f32x2 acc[4];
    if (grp == 0) {  // self-loop term
        uint4 v = table[(size_t)node * 16 + l16];
        f32x2 w0 = (f32x2){dc * dc, dc * dc};
        acc[0] = w0 * up2(v.x);
        acc[1] = w0 * up2(v.y);
        acc[2] = w0 * up2(v.z);
        acc[3] = w0 * up2(v.w);
    } else {
#pragma unroll
        for (int j = 0; j < 4; j++) acc[j] = (f32x2){0.f, 0.f};
    }

    int s = off[node], e = off[node + 1];
    int i = s + grp;
    for (; i + 4 < e; i += 8) {
        int r0 = srcArr[i];
        int r1 = srcArr[i + 4];
        uint4 u0 = table[(size_t)r0 * 16 + l16];
        uint4 u1 = table[(size_t)r1 * 16 + l16];
        float f0 = dc * dinv[r0];
        float f1 = dc * dinv[r1];
        f32x2 n0 = (f32x2){f0, f0};
        f32x2 n1 = (f32x2){f1, f1};
        acc[0] += n0 * up2(u0.x);
        acc[1] += n0 * up2(u0.y);
        acc[2] += n0 * up2(u0.z);
        acc[3] += n0 * up2(u0.w);
        acc[0] += n1 * up2(u1.x);
        acc[1] += n1 * up2(u1.y);
        acc[2] += n1 * up2(u1.z);
        acc[3] += n1 * up2(u1.w);
    }
    if (i < e) {
        int r0 = srcArr[i];
        uint4 u0 = table[(size_t)r0 * 16 + l16];
        float f0 = dc * dinv[r0];
        f32x2 n0 = (f32x2){f0, f0};
        acc[0] += n0 * up2(u0.x);
        acc[1] += n0 * up2(u0.y);
        acc[2] += n0 * up2(u0.z);
        acc[3] += n0 * up2(u0.w);
    }

    b[0] = acc[0].x; b[1] = acc[0].y; b[2] = acc[1].x; b[3] = acc[1].y;
    b[4] = acc[2].x; b[5] = acc[2].y; b[6] = acc[3].x; b[7] = acc[3].y;
#pragma unroll
    for (int j = 0; j < 8; j++) {
        b[j] += __shfl_xor(b[j], 16);
        b[j] += __shfl_xor(b[j], 32);
    }
}

// ---------------- gather passes 1-2: write bf16 table ------------------------
__global__ __launch_bounds__(256) void gather_kernel(const int* __restrict__ off,
                                                     const int* __restrict__ srcArr,
                                                     const float* __restrict__ dinv,
                                                     const ushort16* __restrict__ XWh,
                                                     ushort16* __restrict__ Hh, int n,
                                                     int leaky) {
    int node = blockIdx.x * 4 + (threadIdx.x >> 6);
    if (node >= n) return;
    int lane = threadIdx.x & 63;
    float b[8];
    gather_body(off, srcArr, dinv, (const uint4*)XWh, node, lane, b);
    if ((lane >> 4) == 0) {
        if (leaky) {
#pragma unroll
            for (int j = 0; j < 8; j++) b[j] = (b[j] >= 0.f) ? b[j] : 0.01f * b[j];
        }
        int l16 = lane & 15;
        uint4 o;
        o.x = (uint32)f2bf(b[0]) | ((uint32)f2bf(b[1]) << 16);
        o.y = (uint32)f2bf(b[2]) | ((uint32)f2bf(b[3]) << 16);
        o.z = (uint32)f2bf(b[4]) | ((uint32)f2bf(b[5]) << 16);
        o.w = (uint32)f2bf(b[6]) | ((uint32)f2bf(b[7]) << 16);
        *(uint4*)(Hh + (size_t)node * FEAT + l16 * 8) = o;
    }
}

// ---------------- gather pass 3 FUSED with pool ------------------------------
// Skips the N x 128 table write + re-read: stage 4 nodes' rows in LDS,
// run-aggregate by graph (batch sorted), ~134 atomics/block into Pbuf.
__global__ __launch_bounds__(256) void gatherpool_kernel(const int* __restrict__ off,
                                                         const int* __restrict__ srcArr,
                                                         const float* __restrict__ dinv,
                                                         const ushort16* __restrict__ XWh,
                                                         const int* __restrict__ batch,
                                                         float* __restrict__ Pbuf, int n) {
    __shared__ float sH[4][FEAT];
    __shared__ int sG[4];
    const int w = threadIdx.x >> 6;
    const int node = blockIdx.x * 4 + w;
    const int lane = threadIdx.x & 63;
    const bool valid = node < n;

    float b[8];
    if (valid) {
        gather_body(off, srcArr, dinv, (const uint4*)XWh, node, lane, b);
        if (lane == 0) sG[w] = batch[node];
        if ((lane >> 4) == 0) {
            int l16 = lane & 15;
#pragma unroll
            for (int k = 0; k < 8; k++) sH[w][l16 * 8 + k] = b[k];
        }
    } else if (lane == 0) {
        sG[w] = -1;
    }
    __syncthreads();

    if (threadIdx.x < FEAT) {
        int f = threadIdx.x;
        float acc = 0.f;
        int g = -1;
#pragma unroll
        for (int ww = 0; ww < 4; ww++) {
            int gw = sG[ww];
            if (gw < 0) continue;
            if (gw != g) {
                if (g >= 0) atomicAdd(&Pbuf[(size_t)g * FEAT + f], acc);
                acc = 0.f;
                g = gw;
            }
            acc += sH[ww][f];
        }
        if (g >= 0) atomicAdd(&Pbuf[(size_t)g * FEAT + f], acc);
    }
}

// ---------------- final tiny GEMM: out[g] = P[g] @ W2 (fp32) -----------------
__global__ __launch_bounds__(128) void pgemm_kernel(const float* __restrict__ P,
                                                    const float* __restrict__ W2,
                                                    float* __restrict__ out) {
    __shared__ float sP[FEAT];
    const int g = blockIdx.x;
    const int t = threadIdx.x;
    sP[t] = P[(size_t)g * FEAT + t];
    __syncthreads();
    float o = 0.f;
#pragma unroll 4
    for (int k = 0; k < FEAT; k++) o += sP[k] * W2[(size_t)k * FEAT + t];
    out[(size_t)g * FEAT + t] = o;
}

extern "C" void kernel_launch(void* const* d_in, const int* in_sizes, int n_in,
                              void* d_out, int out_size, void* d_ws, size_t ws_size,
                              hipStream_t stream) {
    const float* x = (const float*)d_in[0];
    const int* ei = (const int*)d_in[1];
    const int* batch = (const int*)d_in[2];
    const float* W0 = (const float*)d_in[3];
    const float* W1 = (const float*)d_in[4];
    const float* W2 = (const float*)d_in[5];
    float* out = (float*)d_out;

    const int N = in_sizes[0] / FEAT;  // 100000
    const int E = in_sizes[1] / 2;     // 640000
    const int G = out_size / FEAT;     // 512

    const int* rowI = ei;
    const int* colI = ei + E;

    char* ws = (char*)d_ws;
    auto take = [&](size_t bytes) {
        char* p = ws;
        ws += (bytes + 15) & ~(size_t)15;
        return p;
    };
    int* counts    = (int*)take((size_t)N * 4);
    int* off       = (int*)take((size_t)(N + 1) * 4);
    int* nxt       = (int*)take((size_t)N * 4);
    float* dinv    = (float*)take((size_t)N * 4);
    int* bsum      = (int*)take(128 * 4);
    int* srcArr    = (int*)take((size_t)E * 4);
    ushort16* W01t = (ushort16*)take((size_t)16384 * 2);
    float* Pbuf    = (float*)take((size_t)G * FEAT * 4);
    ushort16* bufA = (ushort16*)take((size_t)N * FEAT * 2);
    ushort16* bufB = (ushort16*)take((size_t)N * FEAT * 2);

    const int nb = (N + 1023) / 1024;  // 98

    // ---- pre: zero counts + W01 + zero P ----
    pre_kernel<<<196, 256, 0, stream>>>(counts, N, W0, W1, W01t, Pbuf);

    // ---- hist (latency) || gemm tiles [0,1750) ----
    histgemmA_kernel<<<128 * 9, 256, 0, stream>>>(colI, counts, E, x, W01t, bufA, N);

    // ---- scan step 1 ----
    scan_part<<<nb, 256, 0, stream>>>(counts, bsum, N);

    // ---- scan_final (98 blocks, first) || gemm tiles [1750,2500) ----
    scanfinalgemm_kernel<<<nb + 384, 256, 0, stream>>>(counts, bsum, off, nxt, dinv,
                                                       N, nb, x, W01t, bufA);

    // ---- fill (latency) || gemm tiles [2500,6250) ----
    fillgemmB_kernel<<<512 * 7, 256, 0, stream>>>(x, W01t, bufA, N,
                                                  rowI, colI, nxt, srcArr, E);

    const int gatBlocks = (N + 3) / 4;
    // ---- H3 = leaky(A A Y) ----
    gather_kernel<<<gatBlocks, 256, 0, stream>>>(off, srcArr, dinv, bufA, bufB, N, 0);
    gather_kernel<<<gatBlocks, 256, 0, stream>>>(off, srcArr, dinv, bufB, bufA, N, 1);
    // ---- out_partial = pool(A H3) via fused gather+pool ----
    gatherpool_kernel<<<gatBlocks, 256, 0, stream>>>(off, srcArr, dinv, bufA, batch, Pbuf, N);
    // ---- out = P @ W2 ----
    pgemm_kernel<<<G, 128, 0, stream>>>(Pbuf, W2, out);
}